// Round 13
// baseline (170.442 us; speedup 1.0000x reference)
//
#include <hip/hip_runtime.h>
#include <hip/hip_bf16.h>

#define NA 4096
#define HS 128
#define CSTR 136   // proj/reduce LDS row stride (bf16 elems)

typedef unsigned short u16;
typedef unsigned long long u64;
using bf16x8  = __attribute__((ext_vector_type(8))) short;
using f32x4   = __attribute__((ext_vector_type(4))) float;
using ushort8 = __attribute__((ext_vector_type(8))) unsigned short;
using u32x4   = __attribute__((ext_vector_type(4))) unsigned;

// 1/sqrt(dk)=0.25 * log2(e) * 0.5 (K-dim duplication in the 16x16x32 MFMA)
#define QSCALE 0.18033688011112042f

static __device__ __forceinline__ u16 f2bf(float f) {
    unsigned u = __builtin_bit_cast(unsigned, f);
    u += 0x7FFFu + ((u >> 16) & 1u);
    return (u16)(u >> 16);
}

// packed bf16 pair via HIP intrinsic (backend-managed cvt_pk; NO inline asm —
// plain "=v" asm miscompiled under codegen restructure in r3/r6).
static __device__ __forceinline__ unsigned pkbf(float a, float b) {
    float2 f; f.x = a; f.y = b;
    __hip_bfloat162 r = __float22bfloat162_rn(f);
    unsigned u;
    __builtin_memcpy(&u, &r, 4);
    return u;
}

// ---------------------------------------------------------------------------
// Kernel 1: projections + Wo cvt, one launch (proven r12):
//   blocks   0..383: Q/K/V projections via MFMA; weights self-converted
//                    into LDS in fragment order
//   blocks 384..399: Wo -> WoF bf16 fragment order (for reduce_out)
// Outputs:
//   Qbh [head][4096][16]  natural row order
//   Kbh [head][4096][16]  rows PERMUTED within each 64-block by slot(k) so
//       attn's ST MFMA output lands P register-resident for the PV A-operand:
//       slot(k) = ((k>>5)*2+((k>>2)&1))*16 + ((k>>3)&3)*4 + (k&3)
//       => ST[t4] lane (c,q) reg r holds key 32*(t4>>1)+4*(t4&1)+8q+r
//   VtB [kb(64)][dim(128)][key(64)]  (PV B-fragment loads contiguous)
// ---------------------------------------------------------------------------
__global__ __launch_bounds__(256) void proj_pack(
    const float* __restrict__ Xq, const float* __restrict__ Xk, const float* __restrict__ Xv,
    const float* __restrict__ Wq, const float* __restrict__ Wk,
    const float* __restrict__ Wv, const float* __restrict__ Wo,
    const float* __restrict__ bq, const float* __restrict__ bk,
    const float* __restrict__ bv,
    u16* __restrict__ Qbh, u16* __restrict__ Kbh, u16* __restrict__ VtB,
    u16* __restrict__ WoF)
{
    const int blk = blockIdx.x;
    const int t = threadIdx.x;

    __shared__ __align__(16) u16 Ws[16384];
    __shared__ __align__(16) u16 Xs[32 * CSTR];
    __shared__ __align__(16) u16 Cs[32 * CSTR];

    if (blk >= 384) {               // ---- Wo fragment cvt
        const int gid = (blk - 384) * 256 + t;    // 0..4095
        const int off = gid * 4;
        float4 v = *(const float4*)(Wo + off);
        ushort4 o;
        o.x = f2bf(v.x); o.y = f2bf(v.y); o.z = f2bf(v.z); o.w = f2bf(v.w);
        const int j = off >> 7, k0 = off & 127;
        const int j0 = j >> 4, c = j & 15, kk = k0 >> 5, q = (k0 >> 3) & 3;
        *(ushort4*)(WoF + ((j0 * 4 + kk) * 16 + c) * 32 + q * 8 + (k0 & 7)) = o;
        return;
    }

    // ---- projection: blk 0..383
    const int pb = blk;
    const int mat = pb >> 7;
    const float* X = (mat == 0) ? Xq : (mat == 1) ? Xk : Xv;
    const float* Wsrc = (mat == 0) ? Wq : (mat == 1) ? Wk : Wv;
    const float* bsrc = (mat == 0) ? bq : (mat == 1) ? bk : bv;
    const float sc = (mat == 0) ? QSCALE : 1.0f;
    const int r0b = (pb & 127) * 32;

    // self-convert W: thread t covers source elems [t*64, t*64+64)
    {
        const int base = t * 64;
#pragma unroll
        for (int i = 0; i < 16; ++i) {
            const int off = base + i * 4;
            float4 v = *(const float4*)(Wsrc + off);
            ushort4 o;
            o.x = f2bf(v.x * sc); o.y = f2bf(v.y * sc);
            o.z = f2bf(v.z * sc); o.w = f2bf(v.w * sc);
            const int j = off >> 7, k0 = off & 127;
            const int j0 = j >> 4, c2 = j & 15, kk = k0 >> 5, qq = (k0 >> 3) & 3;
            *(ushort4*)(Ws + (j0 * 4 + kk) * 512 + qq * 128 + c2 * 8 + (k0 & 7)) = o;
        }
    }

    // stage X coalesced: thread -> row t>>3, 16 cols at (t&7)*16
    {
        const int r = t >> 3, cb = (t & 7) * 16;
        const float* Xr = X + (size_t)(r0b + r) * HS + cb;
#pragma unroll
        for (int seg = 0; seg < 4; ++seg) {
            float4 f = *(const float4*)(Xr + seg * 4);
            ushort4 u;
            u.x = f2bf(f.x); u.y = f2bf(f.y); u.z = f2bf(f.z); u.w = f2bf(f.w);
            *(ushort4*)(Xs + r * CSTR + cb + seg * 4) = u;
        }
    }
    __syncthreads();

    const int wv = t >> 6, lane = t & 63;
    const int c = lane & 15, q = lane >> 4;
    const int rw = (wv & 1) * 16;        // wave row offset in block
    const int j0b = (wv >> 1) * 4;       // wave col group (4 j0 of 16 cols)

    bf16x8 af[4];
#pragma unroll
    for (int kk = 0; kk < 4; ++kk)
        af[kk] = *(const bf16x8*)(Xs + (rw + c) * CSTR + kk * 32 + q * 8);

    const f32x4 zero = {0.f, 0.f, 0.f, 0.f};
#pragma unroll
    for (int jj = 0; jj < 4; ++jj) {
        const int j0 = j0b + jj;
        f32x4 acc = zero;
#pragma unroll
        for (int kk = 0; kk < 4; ++kk) {
            bf16x8 bf = *(const bf16x8*)(Ws + (j0 * 4 + kk) * 512 + q * 128 + c * 8);
            acc = __builtin_amdgcn_mfma_f32_16x16x32_bf16(af[kk], bf, acc, 0, 0, 0);
        }
        const float bias = bsrc[j0 * 16 + c] * sc;
#pragma unroll
        for (int r = 0; r < 4; ++r)
            Cs[(rw + 4 * q + r) * CSTR + j0 * 16 + c] = f2bf(acc[r] + bias);
    }
    __syncthreads();

    if (mat < 2) {
        u16* dst = (mat == 0) ? Qbh : Kbh;
        const int h8 = t >> 5, r = t & 31;
        const u16* src = Cs + r * CSTR + h8 * 16;
        int drow = r0b + r;
        if (mat == 1) {   // permuted K row slot within the 64-row block
            const int k = (r0b & 32) + r;
            const int slot = ((k >> 5) * 2 + ((k >> 2) & 1)) * 16
                           + ((k >> 3) & 3) * 4 + (k & 3);
            drow = (r0b & ~63) + slot;
        }
        u16* dp = dst + (size_t)h8 * (NA * 16) + (size_t)drow * 16;
        *(bf16x8*)(dp)     = *(const bf16x8*)(src);
        *(bf16x8*)(dp + 8) = *(const bf16x8*)(src + 8);
    } else {
        const int d = t >> 1, s = t & 1;
        const int kb = r0b >> 6, ko = (r0b & 32) + s * 16;
        ushort8 v0, v1;
#pragma unroll
        for (int jj = 0; jj < 8; ++jj) v0[jj] = Cs[(s * 16 + jj) * CSTR + d];
#pragma unroll
        for (int jj = 0; jj < 8; ++jj) v1[jj] = Cs[(s * 16 + 8 + jj) * CSTR + d];
        u16* dp = VtB + (size_t)kb * 8192 + d * 64 + ko;
        *(ushort8*)(dp)     = v0;
        *(ushort8*)(dp + 8) = v1;
    }
}

// ---------------------------------------------------------------------------
// Kernel 2: attention partials. r13: SPLIT mask staging —
//   prologue packs words 0..7 (keys kt0..kt0+511) into Mwp;
//   second half's 4 int4 loads/lane are ISSUED before the barrier but
//   consumed after iteration 7 (T14 issue-early/write-late: loop-A compute
//   covers the load latency); mid-loop __syncthreads publishes words 8..15.
// Pack bit math and inner iteration body byte-identical to r12 (proven).
// Grid (256 tiles, 4 key-splits), 512 thr = 8 waves, wave = one head.
// part[tile][split][head][272] = { O 16x16 f32, l 16 f32 }.
// ---------------------------------------------------------------------------
__global__ __launch_bounds__(512, 4) void attn(
    const int* __restrict__ mask,
    const u16* __restrict__ Qbh, const u16* __restrict__ Kbh, const u16* __restrict__ VtB,
    float* __restrict__ part)
{
    __shared__ __align__(8)  u64 Mwp[16 * 17];   // [query][word], padded stride
    __shared__ __align__(8)  u64 Mtab[16];       // nibble -> {lo16|hi16} x2 expand
    __shared__ __align__(16) unsigned char Msc[8 * 256];  // per-wave nibble scratch (one half)

    const int t = threadIdx.x;
    const int h = t >> 6;        // wave = head
    const int lane = t & 63;
    const int c = lane & 15;
    const int q = lane >> 4;
    const int tile = blockIdx.x, split = blockIdx.y;
    const int i0 = tile * 16;
    const int kt0 = split * 1024;

    // ---- first-half mask pack (words 0..7 <- keys kt0 .. kt0+511).
    // wave h covers rows 2h, 2h+1; per row 2 coalesced int4 chunks of 256 ints.
    {
#pragma unroll
        for (int rr = 0; rr < 2; ++rr) {
            const int* mrow = mask + (size_t)(i0 + h * 2 + rr) * NA + kt0;
            unsigned char* dst = Msc + h * 256 + rr * 128;
#pragma unroll
            for (int ch = 0; ch < 2; ++ch) {
                const int4 v = *(const int4*)(mrow + ch * 256 + lane * 4);
                const unsigned nib = (v.x != 0 ? 1u : 0u) | (v.y != 0 ? 2u : 0u)
                                   | (v.z != 0 ? 4u : 0u) | (v.w != 0 ? 8u : 0u);
                dst[ch * 64 + lane] = (unsigned char)nib;
            }
        }
        // per-wave write->read dependency only (r8/r12-proven pattern)
        if (lane < 16) {
            const int rr = lane >> 3, k = lane & 7;
            const uint4 b16 = *(const uint4*)(Msc + h * 256 + rr * 128 + k * 16);
            unsigned z[4];
            const unsigned xs4[4] = { b16.x, b16.y, b16.z, b16.w };
#pragma unroll
            for (int i = 0; i < 4; ++i) {
                unsigned x = xs4[i];
                x = (x | (x >> 4)) & 0x00FF00FFu;
                x = (x | (x >> 8)) & 0x0000FFFFu;
                z[i] = x;
            }
            Mwp[(h * 2 + rr) * 17 + k] = (u64)(z[0] | (z[1] << 16))
                                       | ((u64)(z[2] | (z[3] << 16)) << 32);
        }
    }

    // ---- ISSUE second-half loads now (keys kt0+512 .. kt0+1023); consumed
    // after iteration 7 — loop A's ~half of the compute covers the latency.
    int4 m2[4];
#pragma unroll
    for (int rr = 0; rr < 2; ++rr)
#pragma unroll
        for (int ch = 0; ch < 2; ++ch)
            m2[rr * 2 + ch] = *(const int4*)(mask + (size_t)(i0 + h * 2 + rr) * NA
                                             + kt0 + 512 + ch * 256 + lane * 4);

    if (t < 16) {
        const unsigned lo = ((t & 1) ? 0xFFFFu : 0u) | ((t & 2) ? 0xFFFF0000u : 0u);
        const unsigned hi = ((t & 4) ? 0xFFFFu : 0u) | ((t & 8) ? 0xFFFF0000u : 0u);
        Mtab[t] = (u64)lo | ((u64)hi << 32);
    }

    const u16* Qh = Qbh + (size_t)h * (NA * 16);
    const u16* Kh = Kbh + (size_t)h * (NA * 16);

    // Q B-fragment (K-halves duplicated; x2 folded into QSCALE); contiguous.
    const bf16x8 qf = *(const bf16x8*)(Qh + (size_t)(i0 + c) * 16 + (q & 1) * 8);

    // ones B-fragment for the lsum MFMA (all lanes = 1.0bf16)
    bf16x8 ones;
#pragma unroll
    for (int i = 0; i < 8; ++i) ones[i] = (short)0x3F80;

    __syncthreads();

    const f32x4 zero = {0.f, 0.f, 0.f, 0.f};
    f32x4 Oacc = zero;
    f32x4 Lacc = zero;

    // prologue: kf for iter 0 (rows are permuted slots; addresses natural)
    bf16x8 kf[4];
#pragma unroll
    for (int t4 = 0; t4 < 4; ++t4)
        kf[t4] = *(const bf16x8*)(Kh + (size_t)(kt0 + t4 * 16 + c) * 16 + (q & 1) * 8);

    // ================= loop A: iters 0..7 (uses Mwp words 0..7) =============
#pragma unroll 1
    for (int it = 0; it < 8; ++it) {
        const int kt = kt0 + it * 64;
        const u16* Vb = VtB + (size_t)(kt >> 6) * 8192 + (h * 16 + c) * 64;

        bf16x8 vf0 = *(const bf16x8*)(Vb + q * 8);
        bf16x8 vf1 = *(const bf16x8*)(Vb + 32 + q * 8);

        f32x4 ST[4];
        __builtin_amdgcn_s_setprio(1);
#pragma unroll
        for (int t4 = 0; t4 < 4; ++t4)
            ST[t4] = __builtin_amdgcn_mfma_f32_16x16x32_bf16(kf[t4], qf, zero, 0, 0, 0);
        __builtin_amdgcn_s_setprio(0);

        const int ktn = kt0 + ((it + 1) & 15) * 64;
#pragma unroll
        for (int t4 = 0; t4 < 4; ++t4)
            kf[t4] = *(const bf16x8*)(Kh + (size_t)(ktn + t4 * 16 + c) * 16 + (q & 1) * 8);

        const u64 w = Mwp[c * 17 + it];
        const unsigned wa = (unsigned)(w >> (8 * q));
        const unsigned wb = (unsigned)(w >> (32 + 8 * q));

        unsigned pl[4], ph[4];
#pragma unroll
        for (int t4 = 0; t4 < 4; ++t4) {
            const unsigned nib = (((t4 & 2) ? wb : wa) >> ((t4 & 1) * 4)) & 15u;
            float p0 = __builtin_amdgcn_exp2f(ST[t4][0]);
            float p1 = __builtin_amdgcn_exp2f(ST[t4][1]);
            float p2 = __builtin_amdgcn_exp2f(ST[t4][2]);
            float p3 = __builtin_amdgcn_exp2f(ST[t4][3]);
            const unsigned lo = pkbf(p0, p1);
            const unsigned hi = pkbf(p2, p3);
            const u64 mex = Mtab[nib];
            pl[t4] = lo & (unsigned)mex;
            ph[t4] = hi & (unsigned)(mex >> 32);
        }
        const u32x4 a0 = { pl[0], ph[0], pl[1], ph[1] };
        const u32x4 a1 = { pl[2], ph[2], pl[3], ph[3] };
        const bf16x8 pf0 = __builtin_bit_cast(bf16x8, a0);
        const bf16x8 pf1 = __builtin_bit_cast(bf16x8, a1);

        __builtin_amdgcn_s_setprio(1);
        Oacc = __builtin_amdgcn_mfma_f32_16x16x32_bf16(pf0, vf0, Oacc, 0, 0, 0);
        Oacc = __builtin_amdgcn_mfma_f32_16x16x32_bf16(pf1, vf1, Oacc, 0, 0, 0);
        Lacc = __builtin_amdgcn_mfma_f32_16x16x32_bf16(pf0, ones, Lacc, 0, 0, 0);
        Lacc = __builtin_amdgcn_mfma_f32_16x16x32_bf16(pf1, ones, Lacc, 0, 0, 0);
        __builtin_amdgcn_s_setprio(0);
    }

    // ---- publish second-half mask (words 8..15) and sync
    {
#pragma unroll
        for (int idx = 0; idx < 4; ++idx) {
            const int rr = idx >> 1, ch = idx & 1;
            const int4 v = m2[idx];
            const unsigned nib = (v.x != 0 ? 1u : 0u) | (v.y != 0 ? 2u : 0u)
                               | (v.z != 0 ? 4u : 0u) | (v.w != 0 ? 8u : 0u);
            Msc[h * 256 + rr * 128 + ch * 64 + lane] = (unsigned char)nib;
        }
        if (lane < 16) {
            const int rr = lane >> 3, k = lane & 7;
            const uint4 b16 = *(const uint4*)(Msc + h * 256 + rr * 128 + k * 16);
            unsigned z[4];
            const unsigned xs4[4] = { b16.x, b16.y, b16.z, b16.w };
#pragma unroll
            for (int i = 0; i < 4; ++i) {
                unsigned x = xs4[i];
                x = (x | (x >> 4)) & 0x00FF00FFu;
                x = (x | (x >> 8)) & 0x0000FFFFu;
                z[i] = x;
            }
            Mwp[(h * 2 + rr) * 17 + 8 + k] = (u64)(z[0] | (z[1] << 16))
                                           | ((u64)(z[2] | (z[3] << 16)) << 32);
        }
    }
    __syncthreads();

    // ================= loop B: iters 8..15 (uses Mwp words 8..15) ===========
#pragma unroll 1
    for (int it = 8; it < 16; ++it) {
        const int kt = kt0 + it * 64;
        const u16* Vb = VtB + (size_t)(kt >> 6) * 8192 + (h * 16 + c) * 64;

        bf16x8 vf0 = *(const bf16x8*)(Vb + q * 8);
        bf16x8 vf1 = *(const bf16x8*)(Vb + 32 + q * 8);

        f32x4 ST[4];
        __builtin_amdgcn_s_setprio(1);
#pragma unroll
        for (int t4 = 0; t4 < 4; ++t4)
            ST[t4] = __builtin_amdgcn_mfma_f32_16x16x32_bf16(kf[t4], qf, zero, 0, 0, 0);
        __builtin_amdgcn_s_setprio(0);

        const int ktn = kt0 + ((it + 1) & 15) * 64;
#pragma unroll
        for (int t4 = 0; t4 < 4; ++t4)
            kf[t4] = *(const bf16x8*)(Kh + (size_t)(ktn + t4 * 16 + c) * 16 + (q & 1) * 8);

        const u64 w = Mwp[c * 17 + it];
        const unsigned wa = (unsigned)(w >> (8 * q));
        const unsigned wb = (unsigned)(w >> (32 + 8 * q));

        unsigned pl[4], ph[4];
#pragma unroll
        for (int t4 = 0; t4 < 4; ++t4) {
            const unsigned nib = (((t4 & 2) ? wb : wa) >> ((t4 & 1) * 4)) & 15u;
            float p0 = __builtin_amdgcn_exp2f(ST[t4][0]);
            float p1 = __builtin_amdgcn_exp2f(ST[t4][1]);
            float p2 = __builtin_amdgcn_exp2f(ST[t4][2]);
            float p3 = __builtin_amdgcn_exp2f(ST[t4][3]);
            const unsigned lo = pkbf(p0, p1);
            const unsigned hi = pkbf(p2, p3);
            const u64 mex = Mtab[nib];
            pl[t4] = lo & (unsigned)mex;
            ph[t4] = hi & (unsigned)(mex >> 32);
        }
        const u32x4 a0 = { pl[0], ph[0], pl[1], ph[1] };
        const u32x4 a1 = { pl[2], ph[2], pl[3], ph[3] };
        const bf16x8 pf0 = __builtin_bit_cast(bf16x8, a0);
        const bf16x8 pf1 = __builtin_bit_cast(bf16x8, a1);

        __builtin_amdgcn_s_setprio(1);
        Oacc = __builtin_amdgcn_mfma_f32_16x16x32_bf16(pf0, vf0, Oacc, 0, 0, 0);
        Oacc = __builtin_amdgcn_mfma_f32_16x16x32_bf16(pf1, vf1, Oacc, 0, 0, 0);
        Lacc = __builtin_amdgcn_mfma_f32_16x16x32_bf16(pf0, ones, Lacc, 0, 0, 0);
        Lacc = __builtin_amdgcn_mfma_f32_16x16x32_bf16(pf1, ones, Lacc, 0, 0, 0);
        __builtin_amdgcn_s_setprio(0);
    }

    float* base = part + (size_t)((tile * 4 + split) * 8 + h) * 272;
#pragma unroll
    for (int r = 0; r < 4; ++r)
        base[(4 * q + r) * 16 + c] = Oacc[r];
    // Lacc: lane (c,q) reg r holds l[4q+r] (all c identical); c==0 lanes write
    if (c == 0) {
#pragma unroll
        for (int r = 0; r < 4; ++r)
            base[256 + 4 * q + r] = Lacc[r];
    }
}

// ---------------------------------------------------------------------------
// Kernel 3: combine 4 split partials, normalize, output projection via MFMA.
// (round-4/7/8/11/12 proven body)
// ---------------------------------------------------------------------------
__global__ __launch_bounds__(256) void reduce_out(
    const float* __restrict__ part, const u16* __restrict__ WoF,
    float* __restrict__ out)
{
    __shared__ __align__(16) u16 xs[16 * CSTR];

    const int t = threadIdx.x;
    const int tile = blockIdx.x;
    const int i0 = tile * 16;
    const float* Pt = part + (size_t)tile * 4 * 8 * 272;

    {
        const int i = t >> 4, d = t & 15;
#pragma unroll
        for (int h = 0; h < 8; ++h) {
            float os = 0.f, ls = 0.f;
#pragma unroll
            for (int s = 0; s < 4; ++s) {
                const float* b = Pt + (size_t)(s * 8 + h) * 272;
                os += b[i * 16 + d];
                ls += b[256 + i];
            }
            xs[i * CSTR + h * 16 + d] = f2bf(os / ls);
        }
    }
    __syncthreads();

    const int wv = t >> 6, lane = t & 63;
    const int c = lane & 15, q = lane >> 4;

    bf16x8 af[4];
#pragma unroll
    for (int kk = 0; kk < 4; ++kk)
        af[kk] = *(const bf16x8*)(xs + c * CSTR + kk * 32 + q * 8);

    const f32x4 zero = {0.f, 0.f, 0.f, 0.f};
#pragma unroll
    for (int jj = 0; jj < 2; ++jj) {
        const int j0 = wv * 2 + jj;
        f32x4 acc = zero;
#pragma unroll
        for (int kk = 0; kk < 4; ++kk) {
            bf16x8 bf = *(const bf16x8*)(WoF + (j0 * 4 + kk) * 512 + c * 32 + q * 8);
            acc = __builtin_amdgcn_mfma_f32_16x16x32_bf16(af[kk], bf, acc, 0, 0, 0);
        }
#pragma unroll
        for (int r = 0; r < 4; ++r)
            out[(size_t)(i0 + 4 * q + r) * HS + j0 * 16 + c] = acc[r];
    }
}

extern "C" void kernel_launch(void* const* d_in, const int* in_sizes, int n_in,
                              void* d_out, int out_size, void* d_ws, size_t ws_size,
                              hipStream_t stream) {
    const float* query = (const float*)d_in[0];
    const float* key   = (const float*)d_in[1];
    const float* value = (const float*)d_in[2];
    const int*   mask  = (const int*)d_in[3];
    const float* Wq    = (const float*)d_in[4];
    const float* bq    = (const float*)d_in[5];
    const float* Wk    = (const float*)d_in[6];
    const float* bk    = (const float*)d_in[7];
    const float* Wv    = (const float*)d_in[8];
    const float* bv    = (const float*)d_in[9];
    const float* Wo    = (const float*)d_in[10];

    u16* Qbh = (u16*)d_ws;                     // 1 MB  [8][4096][16]
    u16* Kbh = Qbh + (size_t)NA * HS;          // 1 MB  [8][4096][16] (permuted)
    u16* VtB = Kbh + (size_t)NA * HS;          // 1 MB  [64][128][64]
    u16* WoF = VtB + (size_t)NA * HS;          // 32 KB (Wo fragments)
    float* partb = (float*)(WoF + 16384);      // 256*4*8*272 f32 = 8.9 MB

    proj_pack<<<400, 256, 0, stream>>>(query, key, value, Wq, Wk, Wv, Wo,
                                       bq, bk, bv, Qbh, Kbh, VtB, WoF);
    attn<<<dim3(256, 4), 512, 0, stream>>>(mask, Qbh, Kbh, VtB, partb);
    reduce_out<<<256, 256, 0, stream>>>(partb, WoF, (float*)d_out);
}

// Round 14
// 167.241 us; speedup vs baseline: 1.0191x; 1.0191x over previous
//
#include <hip/hip_runtime.h>
#include <hip/hip_bf16.h>

#define NA 4096
#define HS 128
#define CSTR 136   // proj/reduce LDS row stride (bf16 elems)

typedef unsigned short u16;
typedef unsigned long long u64;
using bf16x8  = __attribute__((ext_vector_type(8))) short;
using f32x4   = __attribute__((ext_vector_type(4))) float;
using ushort8 = __attribute__((ext_vector_type(8))) unsigned short;
using u32x4   = __attribute__((ext_vector_type(4))) unsigned;

// 1/sqrt(dk)=0.25 * log2(e) * 0.5 (K-dim duplication in the 16x16x32 MFMA)
#define QSCALE 0.18033688011112042f

static __device__ __forceinline__ u16 f2bf(float f) {
    unsigned u = __builtin_bit_cast(unsigned, f);
    u += 0x7FFFu + ((u >> 16) & 1u);
    return (u16)(u >> 16);
}

// packed bf16 pair via HIP intrinsic (backend-managed cvt_pk; NO inline asm —
// plain "=v" asm miscompiled under codegen restructure in r3/r6).
// __hip_bfloat162 is not trivially copyable -> extract via memcpy (free).
static __device__ __forceinline__ unsigned pkbf(float a, float b) {
    float2 f; f.x = a; f.y = b;
    __hip_bfloat162 r = __float22bfloat162_rn(f);
    unsigned u;
    __builtin_memcpy(&u, &r, 4);
    return u;
}

// ---------------------------------------------------------------------------
// Kernel 1: projections + Wo cvt, one launch (proven r12):
//   blocks   0..383: Q/K/V projections via MFMA; weights self-converted
//                    into LDS in fragment order
//   blocks 384..399: Wo -> WoF bf16 fragment order (for reduce_out)
// Outputs:
//   Qbh [head][4096][16]  natural row order
//   Kbh [head][4096][16]  rows PERMUTED within each 64-block by slot(k) so
//       attn's ST MFMA output lands P register-resident for the PV A-operand:
//       slot(k) = ((k>>5)*2+((k>>2)&1))*16 + ((k>>3)&3)*4 + (k&3)
//       => ST[t4] lane (c,q) reg r holds key 32*(t4>>1)+4*(t4&1)+8q+r
//   VtB [kb(64)][dim(128)][key(64)]  (PV B-fragment loads contiguous)
// ---------------------------------------------------------------------------
__global__ __launch_bounds__(256) void proj_pack(
    const float* __restrict__ Xq, const float* __restrict__ Xk, const float* __restrict__ Xv,
    const float* __restrict__ Wq, const float* __restrict__ Wk,
    const float* __restrict__ Wv, const float* __restrict__ Wo,
    const float* __restrict__ bq, const float* __restrict__ bk,
    const float* __restrict__ bv,
    u16* __restrict__ Qbh, u16* __restrict__ Kbh, u16* __restrict__ VtB,
    u16* __restrict__ WoF)
{
    const int blk = blockIdx.x;
    const int t = threadIdx.x;

    __shared__ __align__(16) u16 Ws[16384];
    __shared__ __align__(16) u16 Xs[32 * CSTR];
    __shared__ __align__(16) u16 Cs[32 * CSTR];

    if (blk >= 384) {               // ---- Wo fragment cvt
        const int gid = (blk - 384) * 256 + t;    // 0..4095
        const int off = gid * 4;
        float4 v = *(const float4*)(Wo + off);
        ushort4 o;
        o.x = f2bf(v.x); o.y = f2bf(v.y); o.z = f2bf(v.z); o.w = f2bf(v.w);
        const int j = off >> 7, k0 = off & 127;
        const int j0 = j >> 4, c = j & 15, kk = k0 >> 5, q = (k0 >> 3) & 3;
        *(ushort4*)(WoF + ((j0 * 4 + kk) * 16 + c) * 32 + q * 8 + (k0 & 7)) = o;
        return;
    }

    // ---- projection: blk 0..383
    const int pb = blk;
    const int mat = pb >> 7;
    const float* X = (mat == 0) ? Xq : (mat == 1) ? Xk : Xv;
    const float* Wsrc = (mat == 0) ? Wq : (mat == 1) ? Wk : Wv;
    const float* bsrc = (mat == 0) ? bq : (mat == 1) ? bk : bv;
    const float sc = (mat == 0) ? QSCALE : 1.0f;
    const int r0b = (pb & 127) * 32;

    // self-convert W: thread t covers source elems [t*64, t*64+64)
    // Ws: fragment-ordered, lane-contiguous: elem (j0,kk,c,q,e) at
    //   (j0*4+kk)*512 + q*128 + c*8 + e   (lane (c,q) reads 16B at lane*16)
    {
        const int base = t * 64;
#pragma unroll
        for (int i = 0; i < 16; ++i) {
            const int off = base + i * 4;
            float4 v = *(const float4*)(Wsrc + off);
            ushort4 o;
            o.x = f2bf(v.x * sc); o.y = f2bf(v.y * sc);
            o.z = f2bf(v.z * sc); o.w = f2bf(v.w * sc);
            const int j = off >> 7, k0 = off & 127;
            const int j0 = j >> 4, c2 = j & 15, kk = k0 >> 5, qq = (k0 >> 3) & 3;
            *(ushort4*)(Ws + (j0 * 4 + kk) * 512 + qq * 128 + c2 * 8 + (k0 & 7)) = o;
        }
    }

    // stage X coalesced: thread -> row t>>3, 16 cols at (t&7)*16
    {
        const int r = t >> 3, cb = (t & 7) * 16;
        const float* Xr = X + (size_t)(r0b + r) * HS + cb;
#pragma unroll
        for (int seg = 0; seg < 4; ++seg) {
            float4 f = *(const float4*)(Xr + seg * 4);
            ushort4 u;
            u.x = f2bf(f.x); u.y = f2bf(f.y); u.z = f2bf(f.z); u.w = f2bf(f.w);
            *(ushort4*)(Xs + r * CSTR + cb + seg * 4) = u;
        }
    }
    __syncthreads();

    const int wv = t >> 6, lane = t & 63;
    const int c = lane & 15, q = lane >> 4;
    const int rw = (wv & 1) * 16;        // wave row offset in block
    const int j0b = (wv >> 1) * 4;       // wave col group (4 j0 of 16 cols)

    bf16x8 af[4];
#pragma unroll
    for (int kk = 0; kk < 4; ++kk)
        af[kk] = *(const bf16x8*)(Xs + (rw + c) * CSTR + kk * 32 + q * 8);

    const f32x4 zero = {0.f, 0.f, 0.f, 0.f};
#pragma unroll
    for (int jj = 0; jj < 4; ++jj) {
        const int j0 = j0b + jj;
        f32x4 acc = zero;
#pragma unroll
        for (int kk = 0; kk < 4; ++kk) {
            bf16x8 bf = *(const bf16x8*)(Ws + (j0 * 4 + kk) * 512 + q * 128 + c * 8);
            acc = __builtin_amdgcn_mfma_f32_16x16x32_bf16(af[kk], bf, acc, 0, 0, 0);
        }
        const float bias = bsrc[j0 * 16 + c] * sc;
#pragma unroll
        for (int r = 0; r < 4; ++r)
            Cs[(rw + 4 * q + r) * CSTR + j0 * 16 + c] = f2bf(acc[r] + bias);
    }
    __syncthreads();

    if (mat < 2) {
        u16* dst = (mat == 0) ? Qbh : Kbh;
        const int h8 = t >> 5, r = t & 31;
        const u16* src = Cs + r * CSTR + h8 * 16;
        int drow = r0b + r;
        if (mat == 1) {   // permuted K row slot within the 64-row block
            const int k = (r0b & 32) + r;
            const int slot = ((k >> 5) * 2 + ((k >> 2) & 1)) * 16
                           + ((k >> 3) & 3) * 4 + (k & 3);
            drow = (r0b & ~63) + slot;
        }
        u16* dp = dst + (size_t)h8 * (NA * 16) + (size_t)drow * 16;
        *(bf16x8*)(dp)     = *(const bf16x8*)(src);
        *(bf16x8*)(dp + 8) = *(const bf16x8*)(src + 8);
    } else {
        const int d = t >> 1, s = t & 1;
        const int kb = r0b >> 6, ko = (r0b & 32) + s * 16;
        ushort8 v0, v1;
#pragma unroll
        for (int jj = 0; jj < 8; ++jj) v0[jj] = Cs[(s * 16 + jj) * CSTR + d];
#pragma unroll
        for (int jj = 0; jj < 8; ++jj) v1[jj] = Cs[(s * 16 + 8 + jj) * CSTR + d];
        u16* dp = VtB + (size_t)kb * 8192 + d * 64 + ko;
        *(ushort8*)(dp)     = v0;
        *(ushort8*)(dp + 8) = v1;
    }
}

// ---------------------------------------------------------------------------
// Kernel 2: attention partials (r12-proven, best passing build).
// Staging section packs the mask tile DIRECTLY from global (coalesced int4
// loads -> nibble bytes in LDS -> lane-assembled u64 words); the 64 MB mask
// read rides attn's memory pipe. Bit layout:
// Mwp[r][w] bit j <- mask[i0+r][kt0 + 64w + j].
// Grid (256 tiles, 4 key-splits), 512 thr = 8 waves (each tile read once).
// Inner loop FROZEN (r3/r6 taught: no register-lifetime restructuring; r9
// taught: pipelining is perf-null — compiler already schedules it).
// part[tile][split][head][272] = { O 16x16 f32, l 16 f32 }.
// ---------------------------------------------------------------------------
__global__ __launch_bounds__(512, 4) void attn(
    const int* __restrict__ mask,
    const u16* __restrict__ Qbh, const u16* __restrict__ Kbh, const u16* __restrict__ VtB,
    float* __restrict__ part)
{
    __shared__ __align__(8)  u64 Mwp[16 * 17];   // [query][word], padded stride
    __shared__ __align__(8)  u64 Mtab[16];       // nibble -> {lo16|hi16} x2 expand
    __shared__ __align__(16) unsigned char Msc[8 * 512];  // per-wave nibble scratch

    const int t = threadIdx.x;
    const int h = t >> 6;        // wave = head
    const int lane = t & 63;
    const int c = lane & 15;
    const int q = lane >> 4;
    const int tile = blockIdx.x, split = blockIdx.y;
    const int i0 = tile * 16;
    const int kt0 = split * 1024;

    // ---- direct mask pack: wave h covers rows 2h, 2h+1 (16 rows total).
    {
#pragma unroll
        for (int rr = 0; rr < 2; ++rr) {
            const int row = h * 2 + rr;
            const int* mrow = mask + (size_t)(i0 + row) * NA + kt0;
            unsigned char* dst = Msc + h * 512 + rr * 256;
#pragma unroll
            for (int ch = 0; ch < 4; ++ch) {
                const int4 v = *(const int4*)(mrow + ch * 256 + lane * 4);
                const unsigned nib = (v.x != 0 ? 1u : 0u) | (v.y != 0 ? 2u : 0u)
                                   | (v.z != 0 ? 4u : 0u) | (v.w != 0 ? 8u : 0u);
                dst[ch * 64 + lane] = (unsigned char)nib;
            }
        }
        // per-wave write->read dependency only (r8-proven pattern)
        if (lane < 32) {
            const int rr = lane >> 4, k = lane & 15;
            const int row = h * 2 + rr;
            const uint4 b16 = *(const uint4*)(Msc + h * 512 + rr * 256 + k * 16);
            unsigned z[4];
            const unsigned xs4[4] = { b16.x, b16.y, b16.z, b16.w };
#pragma unroll
            for (int i = 0; i < 4; ++i) {
                unsigned x = xs4[i];
                x = (x | (x >> 4)) & 0x00FF00FFu;
                x = (x | (x >> 8)) & 0x0000FFFFu;
                z[i] = x;
            }
            Mwp[row * 17 + k] = (u64)(z[0] | (z[1] << 16))
                              | ((u64)(z[2] | (z[3] << 16)) << 32);
        }
    }
    if (t < 16) {
        const unsigned lo = ((t & 1) ? 0xFFFFu : 0u) | ((t & 2) ? 0xFFFF0000u : 0u);
        const unsigned hi = ((t & 4) ? 0xFFFFu : 0u) | ((t & 8) ? 0xFFFF0000u : 0u);
        Mtab[t] = (u64)lo | ((u64)hi << 32);
    }

    const u16* Qh = Qbh + (size_t)h * (NA * 16);
    const u16* Kh = Kbh + (size_t)h * (NA * 16);

    // Q B-fragment (K-halves duplicated; x2 folded into QSCALE); contiguous.
    const bf16x8 qf = *(const bf16x8*)(Qh + (size_t)(i0 + c) * 16 + (q & 1) * 8);

    // ones B-fragment for the lsum MFMA (all lanes = 1.0bf16)
    bf16x8 ones;
#pragma unroll
    for (int i = 0; i < 8; ++i) ones[i] = (short)0x3F80;

    __syncthreads();

    const f32x4 zero = {0.f, 0.f, 0.f, 0.f};
    f32x4 Oacc = zero;
    f32x4 Lacc = zero;

    // prologue: kf for iter 0 (rows are permuted slots; addresses natural)
    bf16x8 kf[4];
#pragma unroll
    for (int t4 = 0; t4 < 4; ++t4)
        kf[t4] = *(const bf16x8*)(Kh + (size_t)(kt0 + t4 * 16 + c) * 16 + (q & 1) * 8);

#pragma unroll 1
    for (int it = 0; it < 16; ++it) {
        const int kt = kt0 + it * 64;
        const u16* Vb = VtB + (size_t)(kt >> 6) * 8192 + (h * 16 + c) * 64;

        // V B-fragments (contiguous 1KB per load across the wave)
        bf16x8 vf0 = *(const bf16x8*)(Vb + q * 8);
        bf16x8 vf1 = *(const bf16x8*)(Vb + 32 + q * 8);

        // S^T tiles; permuted K => lane (c,q) reg r = S[q_row c][key B(t4)+8q+r]
        f32x4 ST[4];
        __builtin_amdgcn_s_setprio(1);
#pragma unroll
        for (int t4 = 0; t4 < 4; ++t4)
            ST[t4] = __builtin_amdgcn_mfma_f32_16x16x32_bf16(kf[t4], qf, zero, 0, 0, 0);
        __builtin_amdgcn_s_setprio(0);

        // prefetch next iter's kf (wraps to kt0 on last iter; data unused)
        const int ktn = kt0 + ((it + 1) & 15) * 64;
#pragma unroll
        for (int t4 = 0; t4 < 4; ++t4)
            kf[t4] = *(const bf16x8*)(Kh + (size_t)(ktn + t4 * 16 + c) * 16 + (q & 1) * 8);

        // mask bits, natural order: key B(t4)+8q+r; B = 32*(t4>>1)+4*(t4&1)
        const u64 w = Mwp[c * 17 + it];
        const unsigned wa = (unsigned)(w >> (8 * q));          // keys 8q+...
        const unsigned wb = (unsigned)(w >> (32 + 8 * q));     // keys 32+8q+...

        unsigned pl[4], ph[4];
#pragma unroll
        for (int t4 = 0; t4 < 4; ++t4) {
            const unsigned nib = (((t4 & 2) ? wb : wa) >> ((t4 & 1) * 4)) & 15u;
            float p0 = __builtin_amdgcn_exp2f(ST[t4][0]);
            float p1 = __builtin_amdgcn_exp2f(ST[t4][1]);
            float p2 = __builtin_amdgcn_exp2f(ST[t4][2]);
            float p3 = __builtin_amdgcn_exp2f(ST[t4][3]);
            const unsigned lo = pkbf(p0, p1);
            const unsigned hi = pkbf(p2, p3);
            const u64 mex = Mtab[nib];           // conflict-light 16-entry table
            pl[t4] = lo & (unsigned)mex;
            ph[t4] = hi & (unsigned)(mex >> 32);
        }
        const u32x4 a0 = { pl[0], ph[0], pl[1], ph[1] };   // keys 8q+0..7
        const u32x4 a1 = { pl[2], ph[2], pl[3], ph[3] };   // keys 32+8q+0..7
        const bf16x8 pf0 = __builtin_bit_cast(bf16x8, a0);
        const bf16x8 pf1 = __builtin_bit_cast(bf16x8, a1);

        // O += P @ V ; L += P @ ones (masked row-sums)
        __builtin_amdgcn_s_setprio(1);
        Oacc = __builtin_amdgcn_mfma_f32_16x16x32_bf16(pf0, vf0, Oacc, 0, 0, 0);
        Oacc = __builtin_amdgcn_mfma_f32_16x16x32_bf16(pf1, vf1, Oacc, 0, 0, 0);
        Lacc = __builtin_amdgcn_mfma_f32_16x16x32_bf16(pf0, ones, Lacc, 0, 0, 0);
        Lacc = __builtin_amdgcn_mfma_f32_16x16x32_bf16(pf1, ones, Lacc, 0, 0, 0);
        __builtin_amdgcn_s_setprio(0);
    }

    float* base = part + (size_t)((tile * 4 + split) * 8 + h) * 272;
#pragma unroll
    for (int r = 0; r < 4; ++r)
        base[(4 * q + r) * 16 + c] = Oacc[r];
    // Lacc: lane (c,q) reg r holds l[4q+r] (all c identical); c==0 lanes write
    if (c == 0) {
#pragma unroll
        for (int r = 0; r < 4; ++r)
            base[256 + 4 * q + r] = Lacc[r];
    }
}

// ---------------------------------------------------------------------------
// Kernel 3: combine 4 split partials, normalize, output projection via MFMA.
// (round-4/7/8/11/12 proven body)
// ---------------------------------------------------------------------------
__global__ __launch_bounds__(256) void reduce_out(
    const float* __restrict__ part, const u16* __restrict__ WoF,
    float* __restrict__ out)
{
    __shared__ __align__(16) u16 xs[16 * CSTR];

    const int t = threadIdx.x;
    const int tile = blockIdx.x;
    const int i0 = tile * 16;
    const float* Pt = part + (size_t)tile * 4 * 8 * 272;

    {
        const int i = t >> 4, d = t & 15;
#pragma unroll
        for (int h = 0; h < 8; ++h) {
            float os = 0.f, ls = 0.f;
#pragma unroll
            for (int s = 0; s < 4; ++s) {
                const float* b = Pt + (size_t)(s * 8 + h) * 272;
                os += b[i * 16 + d];
                ls += b[256 + i];
            }
            xs[i * CSTR + h * 16 + d] = f2bf(os / ls);
        }
    }
    __syncthreads();

    const int wv = t >> 6, lane = t & 63;
    const int c = lane & 15, q = lane >> 4;

    bf16x8 af[4];
#pragma unroll
    for (int kk = 0; kk < 4; ++kk)
        af[kk] = *(const bf16x8*)(xs + c * CSTR + kk * 32 + q * 8);

    const f32x4 zero = {0.f, 0.f, 0.f, 0.f};
#pragma unroll
    for (int jj = 0; jj < 2; ++jj) {
        const int j0 = wv * 2 + jj;
        f32x4 acc = zero;
#pragma unroll
        for (int kk = 0; kk < 4; ++kk) {
            bf16x8 bf = *(const bf16x8*)(WoF + (j0 * 4 + kk) * 512 + c * 32 + q * 8);
            acc = __builtin_amdgcn_mfma_f32_16x16x32_bf16(af[kk], bf, acc, 0, 0, 0);
        }
#pragma unroll
        for (int r = 0; r < 4; ++r)
            out[(size_t)(i0 + 4 * q + r) * HS + j0 * 16 + c] = acc[r];
    }
}

extern "C" void kernel_launch(void* const* d_in, const int* in_sizes, int n_in,
                              void* d_out, int out_size, void* d_ws, size_t ws_size,
                              hipStream_t stream) {
    const float* query = (const float*)d_in[0];
    const float* key   = (const float*)d_in[1];
    const float* value = (const float*)d_in[2];
    const int*   mask  = (const int*)d_in[3];
    const float* Wq    = (const float*)d_in[4];
    const float* bq    = (const float*)d_in[5];
    const float* Wk    = (const float*)d_in[6];
    const float* bk    = (const float*)d_in[7];
    const float* Wv    = (const float*)d_in[8];
    const float* bv    = (const float*)d_in[9];
    const float* Wo    = (const float*)d_in[10];

    u16* Qbh = (u16*)d_ws;                     // 1 MB  [8][4096][16]
    u16* Kbh = Qbh + (size_t)NA * HS;          // 1 MB  [8][4096][16] (permuted)
    u16* VtB = Kbh + (size_t)NA * HS;          // 1 MB  [64][128][64]
    u16* WoF = VtB + (size_t)NA * HS;          // 32 KB (Wo fragments)
    float* partb = (float*)(WoF + 16384);      // 256*4*8*272 f32 = 8.9 MB

    proj_pack<<<400, 256, 0, stream>>>(query, key, value, Wq, Wk, Wv, Wo,
                                       bq, bk, bv, Qbh, Kbh, VtB, WoF);
    attn<<<dim3(256, 4), 512, 0, stream>>>(mask, Qbh, Kbh, VtB, partb);
    reduce_out<<<256, 256, 0, stream>>>(partb, WoF, (float*)d_out);
}